// Round 3
// baseline (471.122 us; speedup 1.0000x reference)
//
#include <hip/hip_runtime.h>
#include <hip/hip_fp16.h>
#include <math.h>

__device__ __forceinline__ float2 h2f2(unsigned int u) {
    __half2 h = *reinterpret_cast<__half2*>(&u);
    return __half22float2(h);
}
__device__ __forceinline__ unsigned int f2h2(float a, float b) {
    __half2 h = __floats2half2_rn(a, b);
    return *reinterpret_cast<unsigned int*>(&h);
}

// ---------------- STAGGER-FUSED: GEMM tile + histogram/rank/weighted-degree slice ----------------
// Epilogue stores Y fp16. Histogram phase also accumulates weighted degree (wsum) so the
// CSR-prep chain needs no extra CSR pass (deg_dinv) or premul pass.
__global__ __launch_bounds__(256) void gemm128_hist_kernel(
        const float* __restrict__ X, const float* __restrict__ W, __half* __restrict__ Y, int n,
        const int* __restrict__ dst, const float* __restrict__ ew,
        int* __restrict__ cnt, float* __restrict__ wsum, int* __restrict__ rank, int E) {
    constexpr int CG  = 32;
    constexpr int M   = 64;
    constexpr int RT  = 8;
    constexpr int KC  = 32;
    constexpr int LDX = 132;
    __shared__ float  Xl[M * LDX];      // 33792 B
    __shared__ float4 Wl[KC * CG];      // 16384 B

    const int bid = blockIdx.x;
    const int t = threadIdx.x;
    const int EPB = (E + (int)gridDim.x - 1) / (int)gridDim.x;
    const int eBeg = bid * EPB;
    const int eEnd = min(eBeg + EPB, E);

    if ((bid & 1) == 0) {
        for (int e = eBeg + t; e < eEnd; e += 256) {
            int d = dst[e];
            rank[e] = atomicAdd(&cnt[d], 1);
            atomicAdd(&wsum[d], ew[e]);
        }
    }

    int row0 = bid * M;
    {
        const float4* Xg = (const float4*)X;
        for (int f = t; f < M * 32; f += 256) {
            int r = f >> 5, c4 = f & 31;
            int gr = row0 + r;
            float4 v = make_float4(0.f, 0.f, 0.f, 0.f);
            if (gr < n) v = Xg[(size_t)gr * 32 + c4];
            *(float4*)&Xl[r * LDX + c4 * 4] = v;
        }
    }

    int cg = t % CG;
    int r0 = (t / CG) * RT;

    float4 acc[RT];
#pragma unroll
    for (int r = 0; r < RT; r++) acc[r] = make_float4(0.f, 0.f, 0.f, 0.f);

    const float4* Wg = (const float4*)W;
    for (int kc = 0; kc < 128; kc += KC) {
        __syncthreads();
        for (int f = t; f < KC * CG; f += 256)
            Wl[f] = Wg[(size_t)kc * CG + f];
        __syncthreads();
#pragma unroll 4
        for (int k = 0; k < KC; k += 4) {
            float4 b0 = Wl[(k + 0) * CG + cg];
            float4 b1 = Wl[(k + 1) * CG + cg];
            float4 b2 = Wl[(k + 2) * CG + cg];
            float4 b3 = Wl[(k + 3) * CG + cg];
#pragma unroll
            for (int r = 0; r < RT; r++) {
                float4 a = *(float4*)&Xl[(r0 + r) * LDX + kc + k];
                acc[r].x += a.x * b0.x + a.y * b1.x + a.z * b2.x + a.w * b3.x;
                acc[r].y += a.x * b0.y + a.y * b1.y + a.z * b2.y + a.w * b3.y;
                acc[r].z += a.x * b0.z + a.y * b1.z + a.z * b2.z + a.w * b3.z;
                acc[r].w += a.x * b0.w + a.y * b1.w + a.z * b2.w + a.w * b3.w;
            }
        }
    }

#pragma unroll
    for (int r = 0; r < RT; r++) {
        int gr = row0 + r0 + r;
        if (gr < n) {
            uint2 u = make_uint2(f2h2(acc[r].x, acc[r].y), f2h2(acc[r].z, acc[r].w));
            *(uint2*)&Y[(size_t)gr * 128 + cg * 4] = u;
        }
    }

    if (bid & 1) {
        for (int e = eBeg + t; e < eEnd; e += 256) {
            int d = dst[e];
            rank[e] = atomicAdd(&cnt[d], 1);
            atomicAdd(&wsum[d], ew[e]);
        }
    }
}

// exclusive scan, stage 1
__global__ __launch_bounds__(256) void scan_block(const int* __restrict__ in, int* __restrict__ out,
                                                  int* __restrict__ bsum, int n) {
    __shared__ int s[256];
    int tid = threadIdx.x;
    int base = blockIdx.x * 1024 + tid * 4;
    int a0 = (base + 0 < n) ? in[base + 0] : 0;
    int a1 = (base + 1 < n) ? in[base + 1] : 0;
    int a2 = (base + 2 < n) ? in[base + 2] : 0;
    int a3 = (base + 3 < n) ? in[base + 3] : 0;
    int tsum = a0 + a1 + a2 + a3;
    s[tid] = tsum;
    __syncthreads();
    for (int off = 1; off < 256; off <<= 1) {
        int v = (tid >= off) ? s[tid - off] : 0;
        __syncthreads();
        s[tid] += v;
        __syncthreads();
    }
    int texcl = s[tid] - tsum;
    if (base + 0 < n) out[base + 0] = texcl;
    if (base + 1 < n) out[base + 1] = texcl + a0;
    if (base + 2 < n) out[base + 2] = texcl + a0 + a1;
    if (base + 3 < n) out[base + 3] = texcl + a0 + a1 + a2;
    if (tid == 255) bsum[blockIdx.x] = s[255];
}

// stage 2
__global__ __launch_bounds__(256) void scan_bsums(int* __restrict__ bsum, int nb) {
    __shared__ int s[256];
    __shared__ int carry_s;
    int tid = threadIdx.x;
    if (tid == 0) carry_s = 0;
    __syncthreads();
    for (int base = 0; base < nb; base += 256) {
        int v = (base + tid < nb) ? bsum[base + tid] : 0;
        int orig = v;
        s[tid] = v;
        __syncthreads();
        for (int off = 1; off < 256; off <<= 1) {
            int u = (tid >= off) ? s[tid - off] : 0;
            __syncthreads();
            s[tid] += u;
            __syncthreads();
        }
        int carry = carry_s;
        int excl = s[tid] - orig + carry;
        if (base + tid < nb) bsum[base + tid] = excl;
        int tot = s[255];
        __syncthreads();
        if (tid == 0) carry_s = carry + tot;
        __syncthreads();
    }
}

// stage 3
__global__ void scan_add(int* __restrict__ rowptr, const int* __restrict__ bscan, int n) {
    int t = blockIdx.x * blockDim.x + threadIdx.x;
    if (t < n) rowptr[t] += bscan[t >> 10];
}

// elementwise dinv from weighted degree (+1 for self-loop)
__global__ void dinv_kernel(const float* __restrict__ wsum, float* __restrict__ dinv, int n) {
    int i = blockIdx.x * blockDim.x + threadIdx.x;
    if (i >= n) return;
    dinv[i] = 1.0f / sqrtf(wsum[i] + 1.0f);
}

// atomic-free CSR placement; weight stored PRE-MULTIPLIED by dinv[src]
__global__ void scatter_pairs(const int* __restrict__ src, const int* __restrict__ dst,
                              const float* __restrict__ ew, const int* __restrict__ rowptr,
                              const int* __restrict__ rank, const float* __restrict__ dinv,
                              int2* __restrict__ pairs, int E) {
    int e = blockIdx.x * blockDim.x + threadIdx.x;
    if (e >= E) return;
    int d = dst[e];
    int s = src[e];
    int p = rowptr[d] + rank[e];
    pairs[p] = make_int2(s, __float_as_int(ew[e] * dinv[s]));
}

// ---------------- FUSED layer-1 gather + ReLU + matvec h1@W2 ----------------
// Latency-bound gather: clamped 8-edge batches (no serial tail) + software-pipelined
// pairs prefetch (next batch's pairs issued during current batch's H loads/FMAs).
__global__ __launch_bounds__(512, 4) void gather_mv_kernel(const __half* __restrict__ H,
                                                           const int* __restrict__ rowptr,
                                                           const int2* __restrict__ pairs,
                                                           const float* __restrict__ dinv,
                                                           const float* __restrict__ bias,
                                                           const float* __restrict__ W2,
                                                           __half* __restrict__ Z, int n) {
    __shared__ float h1s[16 * 128];    // 8 KB
    __shared__ float w2s[128 * 64];    // 32 KB, full W2
    const int t = threadIdx.x;
    const int nl = t >> 5;
    const int c4 = t & 31;
    const int node = blockIdx.x * 16 + nl;

    // stage full W2 (coalesced; L2-hot after first blocks)
    {
        const float4* W2g = (const float4*)W2;
        float4* w2s4 = (float4*)w2s;
#pragma unroll
        for (int f = 0; f < 4; f++) w2s4[f * 512 + t] = W2g[f * 512 + t];
    }

    float4 acc[4];
#pragma unroll
    for (int i = 0; i < 4; i++) acc[i] = make_float4(0.f, 0.f, 0.f, 0.f);

    float di = 0.f;
    int beg = 0, end = 0;
    if (node < n) {
        beg = rowptr[node]; end = rowptr[node + 1];
        di = dinv[node];
        uint2 hv = *(const uint2*)&H[(size_t)node * 128 + c4 * 4];
        float2 f01 = h2f2(hv.x), f23 = h2f2(hv.y);
        acc[0].x = f01.x * di; acc[0].y = f01.y * di;
        acc[0].z = f23.x * di; acc[0].w = f23.y * di;
    }

    if (beg < end) {
        int2 pc[8];
#pragma unroll
        for (int i = 0; i < 8; i++) {
            int jj = beg + i;
            pc[i] = pairs[jj < end ? jj : beg];
        }
        for (int j = beg; j < end; j += 8) {
            // issue H loads for current batch (independent)
            uint2 v[8];
#pragma unroll
            for (int i = 0; i < 8; i++)
                v[i] = *(const uint2*)&H[(size_t)(unsigned)pc[i].x * 128 + c4 * 4];
            // prefetch next pairs batch (clamped; consumed next iteration)
            int2 pn[8];
            int jn = j + 8;
#pragma unroll
            for (int i = 0; i < 8; i++) {
                int jj = jn + i;
                pn[i] = pairs[jj < end ? jj : beg];
            }
            // consume current batch (masked weights for clamped slots)
#pragma unroll
            for (int i = 0; i < 8; i++) {
                float w = (j + i < end) ? __int_as_float(pc[i].y) : 0.f;
                float2 g01 = h2f2(v[i].x), g23 = h2f2(v[i].y);
                acc[i & 3].x += g01.x * w; acc[i & 3].y += g01.y * w;
                acc[i & 3].z += g23.x * w; acc[i & 3].w += g23.y * w;
            }
#pragma unroll
            for (int i = 0; i < 8; i++) pc[i] = pn[i];
        }
    }

    float4 a0 = make_float4(0.f, 0.f, 0.f, 0.f);
    if (node < n) {
        float4 bb = ((const float4*)bias)[c4];
        a0.x = fmaxf(((acc[0].x + acc[1].x) + (acc[2].x + acc[3].x)) * di + bb.x, 0.f);
        a0.y = fmaxf(((acc[0].y + acc[1].y) + (acc[2].y + acc[3].y)) * di + bb.y, 0.f);
        a0.z = fmaxf(((acc[0].z + acc[1].z) + (acc[2].z + acc[3].z)) * di + bb.z, 0.f);
        a0.w = fmaxf(((acc[0].w + acc[1].w) + (acc[2].w + acc[3].w)) * di + bb.w, 0.f);
    }
    *(float4*)&h1s[nl * 128 + c4 * 4] = a0;
    __syncthreads();   // the ONLY barrier: covers w2s staging + h1s

    // matvec: z[node][2c4], z[node][2c4+1]
    float z0 = 0.f, z1 = 0.f;
    const float* hrow = &h1s[nl * 128];
    const float2* w2c = (const float2*)w2s;   // [128][32] float2
#pragma unroll 8
    for (int k = 0; k < 128; k++) {
        float hk = hrow[k];                   // LDS broadcast within node group
        float2 w = w2c[k * 32 + c4];
        z0 += hk * w.x;
        z1 += hk * w.y;
    }
    if (node < n) *(unsigned int*)&Z[(size_t)node * 64 + c4 * 2] = f2h2(z0, z1);
}

// ---------------- CSR segmented gather-reduce (layer 2, C=64) over fp16 rows ----------------
// Same clamped-batch + pairs-prefetch pipeline. 16 lanes/node.
__global__ __launch_bounds__(256, 4) void gather_reduce64(const __half* __restrict__ H,
                                                          const int* __restrict__ rowptr,
                                                          const int2* __restrict__ pairs,
                                                          const float* __restrict__ dinv,
                                                          const float* __restrict__ bias,
                                                          __half* __restrict__ out, int n) {
    constexpr int TPN = 16;
    int t = blockIdx.x * blockDim.x + threadIdx.x;
    int node = t / TPN;
    int c4 = t % TPN;
    if (node >= n) return;
    int beg = rowptr[node], end = rowptr[node + 1];
    float di = dinv[node];
    float4 bb = ((const float4*)bias)[c4];
    float4 acc[4];
    {
        uint2 hv = *(const uint2*)&H[(size_t)node * 64 + c4 * 4];
        float2 f01 = h2f2(hv.x), f23 = h2f2(hv.y);
        acc[0].x = f01.x * di; acc[0].y = f01.y * di;
        acc[0].z = f23.x * di; acc[0].w = f23.y * di;
    }
#pragma unroll
    for (int i = 1; i < 4; i++) acc[i] = make_float4(0.f, 0.f, 0.f, 0.f);

    if (beg < end) {
        int2 pc[8];
#pragma unroll
        for (int i = 0; i < 8; i++) {
            int jj = beg + i;
            pc[i] = pairs[jj < end ? jj : beg];
        }
        for (int j = beg; j < end; j += 8) {
            uint2 v[8];
#pragma unroll
            for (int i = 0; i < 8; i++)
                v[i] = *(const uint2*)&H[(size_t)(unsigned)pc[i].x * 64 + c4 * 4];
            int2 pn[8];
            int jn = j + 8;
#pragma unroll
            for (int i = 0; i < 8; i++) {
                int jj = jn + i;
                pn[i] = pairs[jj < end ? jj : beg];
            }
#pragma unroll
            for (int i = 0; i < 8; i++) {
                float w = (j + i < end) ? __int_as_float(pc[i].y) : 0.f;
                float2 g01 = h2f2(v[i].x), g23 = h2f2(v[i].y);
                acc[i & 3].x += g01.x * w; acc[i & 3].y += g01.y * w;
                acc[i & 3].z += g23.x * w; acc[i & 3].w += g23.y * w;
            }
#pragma unroll
            for (int i = 0; i < 8; i++) pc[i] = pn[i];
        }
    }

    float4 r;
    r.x = ((acc[0].x + acc[1].x) + (acc[2].x + acc[3].x)) * di + bb.x;
    r.y = ((acc[0].y + acc[1].y) + (acc[2].y + acc[3].y)) * di + bb.y;
    r.z = ((acc[0].z + acc[1].z) + (acc[2].z + acc[3].z)) * di + bb.z;
    r.w = ((acc[0].w + acc[1].w) + (acc[2].w + acc[3].w)) * di + bb.w;
    uint2 u = make_uint2(f2h2(r.x, r.y), f2h2(r.z, r.w));
    *(uint2*)&out[(size_t)node * 64 + c4 * 4] = u;
}

// ---------------- decode (Z fp16) ----------------
__global__ void decode_kernel(const __half* __restrict__ Z, const int* __restrict__ ea,
                              const int* __restrict__ eb, float* __restrict__ out, int L) {
    int t = blockIdx.x * blockDim.x + threadIdx.x;
    int e = t >> 4;
    int c = (t & 15) << 2;
    if (e >= L) return;
    uint2 ua = *(const uint2*)&Z[(size_t)ea[e] * 64 + c];
    uint2 ub = *(const uint2*)&Z[(size_t)eb[e] * 64 + c];
    float2 a01 = h2f2(ua.x), a23 = h2f2(ua.y);
    float2 b01 = h2f2(ub.x), b23 = h2f2(ub.y);
    float p = a01.x * b01.x + a01.y * b01.y + a23.x * b23.x + a23.y * b23.y;
    p += __shfl_xor(p, 1);
    p += __shfl_xor(p, 2);
    p += __shfl_xor(p, 4);
    p += __shfl_xor(p, 8);
    if ((t & 15) == 0) out[e] = p;
}

extern "C" void kernel_launch(void* const* d_in, const int* in_sizes, int n_in,
                              void* d_out, int out_size, void* d_ws, size_t ws_size,
                              hipStream_t stream) {
    const float* x   = (const float*)d_in[0];
    const int*   ei  = (const int*)d_in[1];   // [2,E] flat: src = ei, dst = ei+E
    const float* ew  = (const float*)d_in[2];
    const int*   eli = (const int*)d_in[3];   // [2,L] flat
    const float* W1  = (const float*)d_in[4];
    const float* b1  = (const float*)d_in[5];
    const float* W2  = (const float*)d_in[6];
    const float* b2  = (const float*)d_in[7];
    float* out = (float*)d_out;

    const int N = in_sizes[0] / 128;
    const int E = in_sizes[2];
    const int L = in_sizes[3] / 2;
    const int NP = ((N + 255) / 256) * 256;

    float* ws     = (float*)d_ws;
    float* dinv   = ws;                                  // NP
    float* wsum   = ws + NP;                             // NP (zeroed)
    int*   cnt    = (int*)(wsum + NP);                   // NP (needs N+1, zeroed)
    int*   rowptr = cnt + NP;                            // NP (needs N+1)
    int*   bsum   = rowptr + NP;                         // 1024
    int*   rank   = bsum + 1024;                         // E
    int2*  pairs  = (int2*)(rank + E);                   // E int2
    __half* A     = (__half*)(pairs + E);                // NP*128 halfs (h = x@W1)
    __half* B     = (__half*)((float*)(pairs + E) + (size_t)NP * 128);  // NP*64 halfs
    __half* Zf    = A;                                   // z overwrites A region (A dead by then)

    const int n1 = N + 1;
    const int nb = (n1 + 1023) / 1024;

    // zero wsum[NP] and cnt[n1] in one contiguous memset
    hipMemsetAsync(wsum, 0, ((size_t)NP + (size_t)n1) * 4, stream);

    // stagger-fused: layer-1 GEMM tiles + histogram/rank/wsum slices
    const int Gg = (N + 63) / 64;
    gemm128_hist_kernel<<<Gg, 256, 0, stream>>>(x, W1, A, N, ei + E, ew, cnt, wsum, rank, E);

    // dinv (elementwise; replaces CSR deg_dinv + premul)
    dinv_kernel<<<(N + 255) / 256, 256, 0, stream>>>(wsum, dinv, N);

    // CSR finish
    scan_block<<<nb, 256, 0, stream>>>(cnt, rowptr, bsum, n1);
    scan_bsums<<<1, 256, 0, stream>>>(bsum, nb);
    scan_add<<<(n1 + 255) / 256, 256, 0, stream>>>(rowptr, bsum, n1);
    scatter_pairs<<<(E + 255) / 256, 256, 0, stream>>>(ei, ei + E, ew, rowptr, rank, dinv, pairs, E);

    // FUSED: layer-1 aggregate + ReLU + h1@W2  ->  B holds h2' [N,64] fp16
    gather_mv_kernel<<<(N + 15) / 16, 512, 0, stream>>>(A, rowptr, pairs, dinv, b1, W2, B, N);

    // layer-2 aggregate: z = Â h2' + b2  ->  Zf (fp16, overwrites A region)
    gather_reduce64<<<(N * 16 + 255) / 256, 256, 0, stream>>>(B, rowptr, pairs, dinv, b2, Zf, N);

    // decode
    decode_kernel<<<(L * 16 + 255) / 256, 256, 0, stream>>>(Zf, eli, eli + L, out, L);
}

// Round 4
// 421.821 us; speedup vs baseline: 1.1169x; 1.1169x over previous
//
#include <hip/hip_runtime.h>
#include <hip/hip_fp16.h>
#include <math.h>

__device__ __forceinline__ float2 h2f2(unsigned int u) {
    __half2 h = *reinterpret_cast<__half2*>(&u);
    return __half22float2(h);
}
__device__ __forceinline__ unsigned int f2h2(float a, float b) {
    __half2 h = __floats2half2_rn(a, b);
    return *reinterpret_cast<unsigned int*>(&h);
}

// ---------------- STAGGER-FUSED: every block does ONE GEMM tile AND one hist slice ----------------
// Epilogue stores Y fp16 (gather operand downstream). INT atomics only — global fp32
// atomicAdd measured as memory-side 64B RMW (round-3: +99MB WRITE_SIZE, +50us). 
__global__ __launch_bounds__(256) void gemm128_hist_kernel(
        const float* __restrict__ X, const float* __restrict__ W, __half* __restrict__ Y, int n,
        const int* __restrict__ dst, int* __restrict__ cnt, int* __restrict__ rank, int E) {
    constexpr int CG  = 32;
    constexpr int M   = 64;
    constexpr int RT  = 8;
    constexpr int KC  = 32;
    constexpr int LDX = 132;
    __shared__ float  Xl[M * LDX];      // 33792 B
    __shared__ float4 Wl[KC * CG];      // 16384 B

    const int bid = blockIdx.x;
    const int t = threadIdx.x;
    const int EPB = (E + (int)gridDim.x - 1) / (int)gridDim.x;
    const int eBeg = bid * EPB;
    const int eEnd = min(eBeg + EPB, E);

    if ((bid & 1) == 0) {
        for (int e = eBeg + t; e < eEnd; e += 256)
            rank[e] = atomicAdd(&cnt[dst[e]], 1);
    }

    int row0 = bid * M;
    {
        const float4* Xg = (const float4*)X;
        for (int f = t; f < M * 32; f += 256) {
            int r = f >> 5, c4 = f & 31;
            int gr = row0 + r;
            float4 v = make_float4(0.f, 0.f, 0.f, 0.f);
            if (gr < n) v = Xg[(size_t)gr * 32 + c4];
            *(float4*)&Xl[r * LDX + c4 * 4] = v;
        }
    }

    int cg = t % CG;
    int r0 = (t / CG) * RT;

    float4 acc[RT];
#pragma unroll
    for (int r = 0; r < RT; r++) acc[r] = make_float4(0.f, 0.f, 0.f, 0.f);

    const float4* Wg = (const float4*)W;
    for (int kc = 0; kc < 128; kc += KC) {
        __syncthreads();
        for (int f = t; f < KC * CG; f += 256)
            Wl[f] = Wg[(size_t)kc * CG + f];
        __syncthreads();
#pragma unroll 4
        for (int k = 0; k < KC; k += 4) {
            float4 b0 = Wl[(k + 0) * CG + cg];
            float4 b1 = Wl[(k + 1) * CG + cg];
            float4 b2 = Wl[(k + 2) * CG + cg];
            float4 b3 = Wl[(k + 3) * CG + cg];
#pragma unroll
            for (int r = 0; r < RT; r++) {
                float4 a = *(float4*)&Xl[(r0 + r) * LDX + kc + k];
                acc[r].x += a.x * b0.x + a.y * b1.x + a.z * b2.x + a.w * b3.x;
                acc[r].y += a.x * b0.y + a.y * b1.y + a.z * b2.y + a.w * b3.y;
                acc[r].z += a.x * b0.z + a.y * b1.z + a.z * b2.z + a.w * b3.z;
                acc[r].w += a.x * b0.w + a.y * b1.w + a.z * b2.w + a.w * b3.w;
            }
        }
    }

#pragma unroll
    for (int r = 0; r < RT; r++) {
        int gr = row0 + r0 + r;
        if (gr < n) {
            uint2 u = make_uint2(f2h2(acc[r].x, acc[r].y), f2h2(acc[r].z, acc[r].w));
            *(uint2*)&Y[(size_t)gr * 128 + cg * 4] = u;
        }
    }

    if (bid & 1) {
        for (int e = eBeg + t; e < eEnd; e += 256)
            rank[e] = atomicAdd(&cnt[dst[e]], 1);
    }
}

// exclusive scan, stage 1
__global__ __launch_bounds__(256) void scan_block(const int* __restrict__ in, int* __restrict__ out,
                                                  int* __restrict__ bsum, int n) {
    __shared__ int s[256];
    int tid = threadIdx.x;
    int base = blockIdx.x * 1024 + tid * 4;
    int a0 = (base + 0 < n) ? in[base + 0] : 0;
    int a1 = (base + 1 < n) ? in[base + 1] : 0;
    int a2 = (base + 2 < n) ? in[base + 2] : 0;
    int a3 = (base + 3 < n) ? in[base + 3] : 0;
    int tsum = a0 + a1 + a2 + a3;
    s[tid] = tsum;
    __syncthreads();
    for (int off = 1; off < 256; off <<= 1) {
        int v = (tid >= off) ? s[tid - off] : 0;
        __syncthreads();
        s[tid] += v;
        __syncthreads();
    }
    int texcl = s[tid] - tsum;
    if (base + 0 < n) out[base + 0] = texcl;
    if (base + 1 < n) out[base + 1] = texcl + a0;
    if (base + 2 < n) out[base + 2] = texcl + a0 + a1;
    if (base + 3 < n) out[base + 3] = texcl + a0 + a1 + a2;
    if (tid == 255) bsum[blockIdx.x] = s[255];
}

// stage 2
__global__ __launch_bounds__(256) void scan_bsums(int* __restrict__ bsum, int nb) {
    __shared__ int s[256];
    __shared__ int carry_s;
    int tid = threadIdx.x;
    if (tid == 0) carry_s = 0;
    __syncthreads();
    for (int base = 0; base < nb; base += 256) {
        int v = (base + tid < nb) ? bsum[base + tid] : 0;
        int orig = v;
        s[tid] = v;
        __syncthreads();
        for (int off = 1; off < 256; off <<= 1) {
            int u = (tid >= off) ? s[tid - off] : 0;
            __syncthreads();
            s[tid] += u;
            __syncthreads();
        }
        int carry = carry_s;
        int excl = s[tid] - orig + carry;
        if (base + tid < nb) bsum[base + tid] = excl;
        int tot = s[255];
        __syncthreads();
        if (tid == 0) carry_s = carry + tot;
        __syncthreads();
    }
}

// stage 3
__global__ void scan_add(int* __restrict__ rowptr, const int* __restrict__ bscan, int n) {
    int t = blockIdx.x * blockDim.x + threadIdx.x;
    if (t < n) rowptr[t] += bscan[t >> 10];
}

// atomic-free CSR placement: pairs hold (src, RAW ew)
__global__ void scatter_pairs(const int* __restrict__ src, const int* __restrict__ dst,
                              const float* __restrict__ ew, const int* __restrict__ rowptr,
                              const int* __restrict__ rank, int2* __restrict__ pairs, int E) {
    int e = blockIdx.x * blockDim.x + threadIdx.x;
    if (e >= E) return;
    int d = dst[e];
    int p = rowptr[d] + rank[e];
    pairs[p] = make_int2(src[e], __float_as_int(ew[e]));
}

// degree from CONTIGUOUS segment sum of sorted RAW ew (no atomics); dinv = 1/sqrt(deg+1)
__global__ void deg_dinv_kernel(const int2* __restrict__ pairs, const int* __restrict__ rowptr,
                                float* __restrict__ dinv, int n) {
    int i = blockIdx.x * blockDim.x + threadIdx.x;
    if (i >= n) return;
    int beg = rowptr[i], end = rowptr[i + 1];
    float s = 0.f;
    for (int j = beg; j < end; j++) s += __int_as_float(pairs[j].y);
    dinv[i] = 1.0f / sqrtf(s + 1.0f);
}

// fold dinv[src] into the edge weight once
__global__ void premul_kernel(int2* __restrict__ pairs, const float* __restrict__ dinv, int E) {
    int e = blockIdx.x * blockDim.x + threadIdx.x;
    if (e >= E) return;
    int2 p = pairs[e];
    p.y = __float_as_int(__int_as_float(p.y) * dinv[p.x]);
    pairs[e] = p;
}

// ---------------- FUSED layer-1 gather + ReLU + matvec h1@W2 ----------------
// Latency-bound gather: clamped 8-edge batches (no serial tail) + software-pipelined
// pairs prefetch (next batch's pairs issued during current batch's H loads/FMAs).
__global__ __launch_bounds__(512, 4) void gather_mv_kernel(const __half* __restrict__ H,
                                                           const int* __restrict__ rowptr,
                                                           const int2* __restrict__ pairs,
                                                           const float* __restrict__ dinv,
                                                           const float* __restrict__ bias,
                                                           const float* __restrict__ W2,
                                                           __half* __restrict__ Z, int n) {
    __shared__ float h1s[16 * 128];    // 8 KB
    __shared__ float w2s[128 * 64];    // 32 KB, full W2
    const int t = threadIdx.x;
    const int nl = t >> 5;
    const int c4 = t & 31;
    const int node = blockIdx.x * 16 + nl;

    // stage full W2 (coalesced; L2-hot after first blocks)
    {
        const float4* W2g = (const float4*)W2;
        float4* w2s4 = (float4*)w2s;
#pragma unroll
        for (int f = 0; f < 4; f++) w2s4[f * 512 + t] = W2g[f * 512 + t];
    }

    float4 acc[4];
#pragma unroll
    for (int i = 0; i < 4; i++) acc[i] = make_float4(0.f, 0.f, 0.f, 0.f);

    float di = 0.f;
    int beg = 0, end = 0;
    if (node < n) {
        beg = rowptr[node]; end = rowptr[node + 1];
        di = dinv[node];
        uint2 hv = *(const uint2*)&H[(size_t)node * 128 + c4 * 4];
        float2 f01 = h2f2(hv.x), f23 = h2f2(hv.y);
        acc[0].x = f01.x * di; acc[0].y = f01.y * di;
        acc[0].z = f23.x * di; acc[0].w = f23.y * di;
    }

    if (beg < end) {
        int2 pc[8];
#pragma unroll
        for (int i = 0; i < 8; i++) {
            int jj = beg + i;
            pc[i] = pairs[jj < end ? jj : beg];
        }
        for (int j = beg; j < end; j += 8) {
            // issue H loads for current batch (independent)
            uint2 v[8];
#pragma unroll
            for (int i = 0; i < 8; i++)
                v[i] = *(const uint2*)&H[(size_t)(unsigned)pc[i].x * 128 + c4 * 4];
            // prefetch next pairs batch (clamped; consumed next iteration)
            int2 pn[8];
            int jn = j + 8;
#pragma unroll
            for (int i = 0; i < 8; i++) {
                int jj = jn + i;
                pn[i] = pairs[jj < end ? jj : beg];
            }
            // consume current batch (masked weights for clamped slots)
#pragma unroll
            for (int i = 0; i < 8; i++) {
                float w = (j + i < end) ? __int_as_float(pc[i].y) : 0.f;
                float2 g01 = h2f2(v[i].x), g23 = h2f2(v[i].y);
                acc[i & 3].x += g01.x * w; acc[i & 3].y += g01.y * w;
                acc[i & 3].z += g23.x * w; acc[i & 3].w += g23.y * w;
            }
#pragma unroll
            for (int i = 0; i < 8; i++) pc[i] = pn[i];
        }
    }

    float4 a0 = make_float4(0.f, 0.f, 0.f, 0.f);
    if (node < n) {
        float4 bb = ((const float4*)bias)[c4];
        a0.x = fmaxf(((acc[0].x + acc[1].x) + (acc[2].x + acc[3].x)) * di + bb.x, 0.f);
        a0.y = fmaxf(((acc[0].y + acc[1].y) + (acc[2].y + acc[3].y)) * di + bb.y, 0.f);
        a0.z = fmaxf(((acc[0].z + acc[1].z) + (acc[2].z + acc[3].z)) * di + bb.z, 0.f);
        a0.w = fmaxf(((acc[0].w + acc[1].w) + (acc[2].w + acc[3].w)) * di + bb.w, 0.f);
    }
    *(float4*)&h1s[nl * 128 + c4 * 4] = a0;
    __syncthreads();   // the ONLY barrier: covers w2s staging + h1s

    // matvec: z[node][2c4], z[node][2c4+1]
    float z0 = 0.f, z1 = 0.f;
    const float* hrow = &h1s[nl * 128];
    const float2* w2c = (const float2*)w2s;   // [128][32] float2
#pragma unroll 8
    for (int k = 0; k < 128; k++) {
        float hk = hrow[k];                   // LDS broadcast within node group
        float2 w = w2c[k * 32 + c4];
        z0 += hk * w.x;
        z1 += hk * w.y;
    }
    if (node < n) *(unsigned int*)&Z[(size_t)node * 64 + c4 * 2] = f2h2(z0, z1);
}

// ---------------- CSR segmented gather-reduce (layer 2, C=64) over fp16 rows ----------------
// Same clamped-batch + pairs-prefetch pipeline. 16 lanes/node.
__global__ __launch_bounds__(256, 4) void gather_reduce64(const __half* __restrict__ H,
                                                          const int* __restrict__ rowptr,
                                                          const int2* __restrict__ pairs,
                                                          const float* __restrict__ dinv,
                                                          const float* __restrict__ bias,
                                                          __half* __restrict__ out, int n) {
    constexpr int TPN = 16;
    int t = blockIdx.x * blockDim.x + threadIdx.x;
    int node = t / TPN;
    int c4 = t % TPN;
    if (node >= n) return;
    int beg = rowptr[node], end = rowptr[node + 1];
    float di = dinv[node];
    float4 bb = ((const float4*)bias)[c4];
    float4 acc[4];
    {
        uint2 hv = *(const uint2*)&H[(size_t)node * 64 + c4 * 4];
        float2 f01 = h2f2(hv.x), f23 = h2f2(hv.y);
        acc[0].x = f01.x * di; acc[0].y = f01.y * di;
        acc[0].z = f23.x * di; acc[0].w = f23.y * di;
    }
#pragma unroll
    for (int i = 1; i < 4; i++) acc[i] = make_float4(0.f, 0.f, 0.f, 0.f);

    if (beg < end) {
        int2 pc[8];
#pragma unroll
        for (int i = 0; i < 8; i++) {
            int jj = beg + i;
            pc[i] = pairs[jj < end ? jj : beg];
        }
        for (int j = beg; j < end; j += 8) {
            uint2 v[8];
#pragma unroll
            for (int i = 0; i < 8; i++)
                v[i] = *(const uint2*)&H[(size_t)(unsigned)pc[i].x * 64 + c4 * 4];
            int2 pn[8];
            int jn = j + 8;
#pragma unroll
            for (int i = 0; i < 8; i++) {
                int jj = jn + i;
                pn[i] = pairs[jj < end ? jj : beg];
            }
#pragma unroll
            for (int i = 0; i < 8; i++) {
                float w = (j + i < end) ? __int_as_float(pc[i].y) : 0.f;
                float2 g01 = h2f2(v[i].x), g23 = h2f2(v[i].y);
                acc[i & 3].x += g01.x * w; acc[i & 3].y += g01.y * w;
                acc[i & 3].z += g23.x * w; acc[i & 3].w += g23.y * w;
            }
#pragma unroll
            for (int i = 0; i < 8; i++) pc[i] = pn[i];
        }
    }

    float4 r;
    r.x = ((acc[0].x + acc[1].x) + (acc[2].x + acc[3].x)) * di + bb.x;
    r.y = ((acc[0].y + acc[1].y) + (acc[2].y + acc[3].y)) * di + bb.y;
    r.z = ((acc[0].z + acc[1].z) + (acc[2].z + acc[3].z)) * di + bb.z;
    r.w = ((acc[0].w + acc[1].w) + (acc[2].w + acc[3].w)) * di + bb.w;
    uint2 u = make_uint2(f2h2(r.x, r.y), f2h2(r.z, r.w));
    *(uint2*)&out[(size_t)node * 64 + c4 * 4] = u;
}

// ---------------- decode (Z fp16) ----------------
__global__ void decode_kernel(const __half* __restrict__ Z, const int* __restrict__ ea,
                              const int* __restrict__ eb, float* __restrict__ out, int L) {
    int t = blockIdx.x * blockDim.x + threadIdx.x;
    int e = t >> 4;
    int c = (t & 15) << 2;
    if (e >= L) return;
    uint2 ua = *(const uint2*)&Z[(size_t)ea[e] * 64 + c];
    uint2 ub = *(const uint2*)&Z[(size_t)eb[e] * 64 + c];
    float2 a01 = h2f2(ua.x), a23 = h2f2(ua.y);
    float2 b01 = h2f2(ub.x), b23 = h2f2(ub.y);
    float p = a01.x * b01.x + a01.y * b01.y + a23.x * b23.x + a23.y * b23.y;
    p += __shfl_xor(p, 1);
    p += __shfl_xor(p, 2);
    p += __shfl_xor(p, 4);
    p += __shfl_xor(p, 8);
    if ((t & 15) == 0) out[e] = p;
}

extern "C" void kernel_launch(void* const* d_in, const int* in_sizes, int n_in,
                              void* d_out, int out_size, void* d_ws, size_t ws_size,
                              hipStream_t stream) {
    const float* x   = (const float*)d_in[0];
    const int*   ei  = (const int*)d_in[1];   // [2,E] flat: src = ei, dst = ei+E
    const float* ew  = (const float*)d_in[2];
    const int*   eli = (const int*)d_in[3];   // [2,L] flat
    const float* W1  = (const float*)d_in[4];
    const float* b1  = (const float*)d_in[5];
    const float* W2  = (const float*)d_in[6];
    const float* b2  = (const float*)d_in[7];
    float* out = (float*)d_out;

    const int N = in_sizes[0] / 128;
    const int E = in_sizes[2];
    const int L = in_sizes[3] / 2;
    const int NP = ((N + 255) / 256) * 256;

    float* ws     = (float*)d_ws;
    float* dinv   = ws;                                  // NP
    int*   cnt    = (int*)(ws + NP);                     // NP (needs N+1, zeroed)
    int*   rowptr = cnt + NP;                            // NP (needs N+1)
    int*   bsum   = rowptr + NP;                         // 1024
    int*   rank   = bsum + 1024;                         // E
    int2*  pairs  = (int2*)(rank + E);                   // E int2
    __half* A     = (__half*)(pairs + E);                // NP*128 halfs (h = x@W1)
    __half* B     = (__half*)((float*)(pairs + E) + (size_t)NP * 128);  // NP*64 halfs
    __half* Zf    = A;                                   // z overwrites A region (A dead by then)

    const int n1 = N + 1;
    const int nb = (n1 + 1023) / 1024;

    hipMemsetAsync(cnt, 0, (size_t)n1 * 4, stream);

    // stagger-fused: layer-1 GEMM tiles + histogram/rank slices (int atomics only)
    const int Gg = (N + 63) / 64;
    gemm128_hist_kernel<<<Gg, 256, 0, stream>>>(x, W1, A, N, ei + E, cnt, rank, E);

    // CSR finish
    scan_block<<<nb, 256, 0, stream>>>(cnt, rowptr, bsum, n1);
    scan_bsums<<<1, 256, 0, stream>>>(bsum, nb);
    scan_add<<<(n1 + 255) / 256, 256, 0, stream>>>(rowptr, bsum, n1);
    scatter_pairs<<<(E + 255) / 256, 256, 0, stream>>>(ei, ei + E, ew, rowptr, rank, pairs, E);
    deg_dinv_kernel<<<(N + 255) / 256, 256, 0, stream>>>(pairs, rowptr, dinv, N);
    premul_kernel<<<(E + 255) / 256, 256, 0, stream>>>(pairs, dinv, E);

    // FUSED: layer-1 aggregate + ReLU + h1@W2  ->  B holds h2' [N,64] fp16
    gather_mv_kernel<<<(N + 15) / 16, 512, 0, stream>>>(A, rowptr, pairs, dinv, b1, W2, B, N);

    // layer-2 aggregate: z = Â h2' + b2  ->  Zf (fp16, overwrites A region)
    gather_reduce64<<<(N * 16 + 255) / 256, 256, 0, stream>>>(B, rowptr, pairs, dinv, b2, Zf, N);

    // decode
    decode_kernel<<<(L * 16 + 255) / 256, 256, 0, stream>>>(Zf, eli, eli + L, out, L);
}